// Round 8
// baseline (303.432 us; speedup 1.0000x reference)
//
#include <hip/hip_runtime.h>
#include <hip/hip_bf16.h>
#include <math.h>

#define HH 512
#define WW 512
#define BC 48
#define GW 544                    // padded width: 16 left + 512 + 16 right
#define GH 545                    // padded height: 16 top + 512 + 17 bottom
#define PST (GH * GW)             // plane stride in elements (296480)

// prep tile LDS strides
#define SIMS 98                   // bf16 row stride for 96-col staged tile (+2 pad)

typedef __bf16 v8bf __attribute__((ext_vector_type(8)));
typedef float v16f __attribute__((ext_vector_type(16)));

// ---------------------------------------------------------------------------
// Template normalization: Tn = (t - mean)/||t - mean|| per (b,c), bf16 out.
// ---------------------------------------------------------------------------
__global__ __launch_bounds__(256) void k_template(const float* __restrict__ t,
                                                  __hip_bfloat16* __restrict__ tn)
{
    __shared__ float red[256];
    const int bc = blockIdx.x, tid = threadIdx.x;
    const float* tp = t + bc * 1024;
    float v0 = tp[tid], v1 = tp[tid + 256], v2 = tp[tid + 512], v3 = tp[tid + 768];
    red[tid] = v0 + v1 + v2 + v3;
    __syncthreads();
    for (int sft = 128; sft > 0; sft >>= 1) {
        if (tid < sft) red[tid] += red[tid + sft];
        __syncthreads();
    }
    float mean = red[0] * (1.0f / 1024.0f);
    __syncthreads();
    float c0 = v0 - mean, c1 = v1 - mean, c2 = v2 - mean, c3 = v3 - mean;
    red[tid] = c0 * c0 + c1 * c1 + c2 * c2 + c3 * c3;
    __syncthreads();
    for (int sft = 128; sft > 0; sft >>= 1) {
        if (tid < sft) red[tid] += red[tid + sft];
        __syncthreads();
    }
    float norm = sqrtf(red[0]);
    __hip_bfloat16* o = tn + bc * 1024;
    o[tid] = __float2bfloat16(c0 / norm);
    o[tid + 256] = __float2bfloat16(c1 / norm);
    o[tid + 512] = __float2bfloat16(c2 / norm);
    o[tid + 768] = __float2bfloat16(c3 / norm);
}

// ---------------------------------------------------------------------------
// K1: fused 32x32 local-mean centering (round-6 validated, unchanged).
// ---------------------------------------------------------------------------
__global__ __launch_bounds__(256) void k_center2(const float* __restrict__ im,
                                                 __hip_bfloat16* __restrict__ T0)
{
    __shared__ __hip_bfloat16 sim[159 * SIMS];
    __shared__ float hs[159 * 64];
    const int j0 = blockIdx.x * 64;
    const int i0 = blockIdx.y * 128;
    const int plane = blockIdx.z;
    const int tid = threadIdx.x;
    const size_t iplane = (size_t)plane * HH * WW;
    const size_t gplane = (size_t)plane * PST;

    for (int k = tid; k < 159 * 96; k += 256) {
        int r = k / 96, c = k - r * 96;
        int gi = i0 + r - 15, gj = j0 + c - 16;
        float v = (gi >= 0 && gi < HH && gj >= 0 && gj < WW)
                      ? im[iplane + (size_t)gi * WW + gj] : 0.f;
        sim[r * SIMS + c] = __float2bfloat16(v);
    }
    __syncthreads();

    if (tid < 159) {
        const __hip_bfloat16* sr = sim + tid * SIMS;
        float s0 = 0.f;
#pragma unroll
        for (int c = 1; c <= 32; c++) s0 += __bfloat162float(sr[c]);
        hs[tid * 64] = s0;
        for (int j = 1; j < 64; j++) {
            s0 += __bfloat162float(sr[j + 32]) - __bfloat162float(sr[j]);
            hs[tid * 64 + j] = s0;
        }
    }
    __syncthreads();

    const int tc = tid & 63;
    const int lr0 = (tid >> 6) * 32;
    float run = 0.f;
#pragma unroll
    for (int d = 0; d < 32; d++) run += hs[(lr0 + d) * 64 + tc];
    for (int rr = 0; rr < 32; rr++) {
        int lr = lr0 + rr;
        int gi = i0 + lr;
        float imv = __bfloat162float(sim[(lr + 15) * SIMS + tc + 16]);
        float val = imv - run * (1.0f / 1024.0f);
        T0[gplane + (size_t)(16 + gi) * GW + 16 + j0 + tc] = __float2bfloat16(val);
        if (rr < 31) run += hs[(lr + 32) * 64 + tc] - hs[lr * 64 + tc];
    }
    if (blockIdx.x == 0) {
        for (int k = tid; k < 128 * 16; k += 256) {
            int rr = k >> 4, x = k & 15;
            T0[gplane + (size_t)(16 + i0 + rr) * GW + x] = __float2bfloat16(0.f);
        }
    }
    if (blockIdx.x == 7) {
        for (int k = tid; k < 128 * 16; k += 256) {
            int rr = k >> 4, x = k & 15;
            T0[gplane + (size_t)(16 + i0 + rr) * GW + 528 + x] = __float2bfloat16(0.f);
        }
    }
    if (blockIdx.x == 0 && blockIdx.y == 0) {
        for (int k = tid; k < 16 * GW; k += 256)
            T0[gplane + k] = __float2bfloat16(0.f);
    }
    if (blockIdx.x == 0 && blockIdx.y == 3) {
        size_t b = gplane + (size_t)528 * GW;
        for (int k = tid; k < 17 * GW; k += 256)
            T0[b + k] = __float2bfloat16(0.f);
    }
}

// ---------------------------------------------------------------------------
// K2: fused energy normalization (round-6 validated, unchanged).
// ---------------------------------------------------------------------------
__global__ __launch_bounds__(256) void k_norm2(const __hip_bfloat16* __restrict__ T0,
                                               __hip_bfloat16* __restrict__ G0,
                                               __hip_bfloat16* __restrict__ G1)
{
    __shared__ __hip_bfloat16 sim[159 * SIMS];
    __shared__ float hs[159 * 64];
    const int j0 = blockIdx.x * 64;
    const int i0 = blockIdx.y * 128;
    const int plane = blockIdx.z;
    const int tid = threadIdx.x;
    const size_t gplane = (size_t)plane * PST;

    for (int k = tid; k < 159 * 96; k += 256) {
        int r = k / 96, c = k - r * 96;
        sim[r * SIMS + c] = T0[gplane + (size_t)(i0 + 1 + r) * GW + j0 + c];
    }
    __syncthreads();

    if (tid < 159) {
        const __hip_bfloat16* sr = sim + tid * SIMS;
        float s0 = 0.f;
#pragma unroll
        for (int c = 1; c <= 32; c++) {
            float v = __bfloat162float(sr[c]);
            s0 += v * v;
        }
        hs[tid * 64] = s0;
        for (int j = 1; j < 64; j++) {
            float a = __bfloat162float(sr[j + 32]);
            float b = __bfloat162float(sr[j]);
            s0 += a * a - b * b;
            hs[tid * 64 + j] = s0;
        }
    }
    __syncthreads();

    const int tc = tid & 63;
    const int lr0 = (tid >> 6) * 32;
    float run = 0.f;
#pragma unroll
    for (int d = 0; d < 32; d++) run += hs[(lr0 + d) * 64 + tc];
    for (int rr = 0; rr < 32; rr++) {
        int lr = lr0 + rr;
        int gi = i0 + lr;
        int c = j0 + tc;
        float e = sqrtf(fmaxf(run, 0.f));
        float v = __bfloat162float(sim[(lr + 15) * SIMS + tc + 16]) / e;
        __hip_bfloat16 w = __float2bfloat16(v);
        size_t pr = gplane + (size_t)(16 + gi) * GW;
        G0[pr + 16 + c] = w;
        G1[pr + 15 + c] = w;
        if (rr < 31) run += hs[(lr + 32) * 64 + tc] - hs[lr * 64 + tc];
    }
    if (blockIdx.x == 0) {
        for (int k = tid; k < 128 * 16; k += 256) {
            int rr = k >> 4, x = k & 15;
            size_t pr = gplane + (size_t)(16 + i0 + rr) * GW;
            G0[pr + x] = __float2bfloat16(0.f);
            if (x < 15) G1[pr + x] = __float2bfloat16(0.f);
        }
    }
    if (blockIdx.x == 7) {
        for (int k = tid; k < 128 * 17; k += 256) {
            int rr = k / 17, x = k % 17;
            size_t pr = gplane + (size_t)(16 + i0 + rr) * GW;
            G1[pr + 527 + x] = __float2bfloat16(0.f);
            if (x > 0) G0[pr + 527 + x] = __float2bfloat16(0.f);
        }
    }
    if (blockIdx.x == 0 && blockIdx.y == 0) {
        for (int k = tid; k < 16 * GW; k += 256) {
            G0[gplane + k] = __float2bfloat16(0.f);
            G1[gplane + k] = __float2bfloat16(0.f);
        }
    }
    if (blockIdx.x == 0 && blockIdx.y == 3) {
        size_t b = gplane + (size_t)528 * GW;
        for (int k = tid; k < 17 * GW; k += 256) {
            G0[b + k] = __float2bfloat16(0.f);
            G1[b + k] = __float2bfloat16(0.f);
        }
    }
}

// ---------------------------------------------------------------------------
// Correlation: rotating-accumulator MFMA (round-7 validated) with DIRECT
// global B-loads (round-2 validated parity/dual-copy addressing). No LDS,
// no barriers. Fully unrolled 96-step sweep + depth-6 register prefetch
// queue so per-use vmcnt waits overlap ~900-cyc HBM latency across waves.
// Per wave: 32 output cols x 64 output rows.
// ---------------------------------------------------------------------------
#define PFD 6                     // prefetch depth (rows ahead)

__global__ __launch_bounds__(256) void k_corr_mfma(const __hip_bfloat16* __restrict__ G0,
                                                   const __hip_bfloat16* __restrict__ G1,
                                                   const __hip_bfloat16* __restrict__ Tn,
                                                   float* __restrict__ out)
{
    const int tid = threadIdx.x;
    const int wid = tid >> 6;
    const int lane = tid & 63;
    const int n = lane & 31;
    const int h = lane >> 5;
    const int j0w = blockIdx.x * 128 + wid * 32;
    const int i0 = blockIdx.y * 64;
    const int plane = blockIdx.z;

    // A-operand: Tn fragments (whole template in registers)
    const v8bf* tp = (const v8bf*)(Tn + (size_t)plane * 1024 + n * 32 + 8 * h);
    const v8bf a0 = tp[0];
    const v8bf a1 = tp[2];

    // B pointer (round-2 validated): parity-select G0/G1 so 16B loads are
    // 4B-aligned. Sweep rows r = i0-15 .. i0+80 -> phys rows i0+1 .. i0+96.
    const int c0 = j0w + n - 15 + 8 * h;
    const int sel = c0 & 1;
    const __hip_bfloat16* gsel = sel ? G1 : G0;
    const __hip_bfloat16* pb = gsel + (size_t)plane * PST
                             + (size_t)(i0 + 1) * GW + 16 + (c0 - sel);

    float C[16];
#pragma unroll
    for (int s = 0; s < 16; s++) C[s] = 0.f;

    float* outp = out + (size_t)plane * HH * WW + j0w + n;

    // prime the prefetch queue
    v8bf qb0[PFD], qb1[PFD];
#pragma unroll
    for (int d = 0; d < PFD; ++d) {
        const v8bf* rp = (const v8bf*)(pb + (size_t)d * GW);
        qb0[d] = rp[0];
        qb1[d] = rp[2];
    }

#pragma unroll
    for (int T = 0; T < 96; ++T) {
        const int slot = T % PFD;            // static under full unroll
        v16f c;
#pragma unroll
        for (int q = 0; q < 16; ++q) c[q] = C[q];
        c = __builtin_amdgcn_mfma_f32_32x32x16_bf16(a1, qb1[slot], c, 0, 0, 0);
        c = __builtin_amdgcn_mfma_f32_32x32x16_bf16(a0, qb0[slot], c, 0, 0, 0);
        // refill the consumed slot with row T+PFD
        if (T + PFD < 96) {
            const v8bf* rp = (const v8bf*)(pb + (size_t)(T + PFD) * GW);
            qb0[slot] = rp[0];
            qb1[slot] = rp[2];
        }
        // retire: slot b31 (h1 lanes, reg 15) holds a complete output row
        if (T >= 31 && T <= 94) {
            if (h) {
                const int ret = i0 - 31 + T;
                outp[(size_t)ret * WW] = c[15];
            }
        }
        // rotate b -> b+1 (4 half-crossings + within-lane renames)
        float t3  = __shfl_xor(c[3], 32);
        float t7  = __shfl_xor(c[7], 32);
        float t11 = __shfl_xor(c[11], 32);
        float t15 = __shfl_xor(c[15], 32);
        C[0]  = h ? t3  : 0.f;
        C[4]  = h ? t7  : t3;
        C[8]  = h ? t11 : t7;
        C[12] = h ? t15 : t11;
#pragma unroll
        for (int g = 0; g < 4; ++g)
#pragma unroll
            for (int k = 1; k < 4; ++k)
                C[4 * g + k] = c[4 * g + k - 1];
    }
}

// ---------------------------------------------------------------------------
// Orchestration.
//   d_out : T0 (un-normalized padded bf16 im_c) -> final output
//   d_ws  : G0, G1 (bf16 padded dual copies), Tn (bf16)  — ~57 MB
// ---------------------------------------------------------------------------
extern "C" void kernel_launch(void* const* d_in, const int* in_sizes, int n_in,
                              void* d_out, int out_size, void* d_ws, size_t ws_size,
                              hipStream_t stream)
{
    const float* im = (const float*)d_in[0];
    const float* tmpl = (const float*)d_in[1];
    float* outp = (float*)d_out;
    __hip_bfloat16* T0 = (__hip_bfloat16*)d_out;
    __hip_bfloat16* G0 = (__hip_bfloat16*)d_ws;
    __hip_bfloat16* G1 = G0 + (size_t)BC * PST;
    __hip_bfloat16* Tn = G1 + (size_t)BC * PST;

    k_template<<<48, 256, 0, stream>>>(tmpl, Tn);
    k_center2<<<dim3(8, 4, BC), 256, 0, stream>>>(im, T0);
    k_norm2<<<dim3(8, 4, BC), 256, 0, stream>>>(T0, G0, G1);
    k_corr_mfma<<<dim3(4, 8, BC), 256, 0, stream>>>(G0, G1, Tn, outp);
}